// Round 3
// baseline (1346.322 us; speedup 1.0000x reference)
//
#include <hip/hip_runtime.h>

typedef _Float16 f16x8 __attribute__((ext_vector_type(8)));
typedef _Float16 f16x4 __attribute__((ext_vector_type(4)));
typedef float f32x4 __attribute__((ext_vector_type(4)));

static constexpr int NROWS = 65536;

// ---------------------------------------------------------------------------
// Workspace byte offsets (total 142,635,264 B — same as accepted round 2)
// ---------------------------------------------------------------------------
static constexpr size_t OB_BG0  = 0;                        // 1536*4
static constexpr size_t OB_BG1  = OB_BG0 + 6144;            // 1536*4
static constexpr size_t OB_W1H  = OB_BG1 + 6144;            // 1536*768*2 (frag-swizzled)
static constexpr size_t OB_W1L  = OB_W1H + 2359296;
static constexpr size_t OB_W2H  = OB_W1L + 2359296;         // 1536*512*2 (frag-swizzled)
static constexpr size_t OB_W2L  = OB_W2H + 1572864;
static constexpr size_t OB_E    = OB_W2L + 1572864;         // 65536*2*4
static constexpr size_t OB_PMAT = OB_E + 524288;            // 1024*4*4
static constexpr size_t OB_NUM  = OB_PMAT + 16384;          // 256 (padded)
static constexpr size_t OB_H    = OB_NUM + 256;             // 65536*512*4 (f32 row-major)
// Aliased into the H region — all consumers finish before gemm1 writes H:
static constexpr size_t OB_PSUM  = OB_H;                    // 256*768*4
static constexpr size_t OB_PSUM2 = OB_PSUM + 786432;        // 256*768*4
static constexpr size_t OB_SF    = OB_PSUM2 + 786432;       // 768*4
static constexpr size_t OB_TF    = OB_SF + 3072;            // 768*4

// ---------------------------------------------------------------------------
// Helpers
// ---------------------------------------------------------------------------
__device__ __forceinline__ float sigm_(float x) { return 1.f / (1.f + __expf(-x)); }
__device__ __forceinline__ float tanh_(float x) {
  x = fminf(fmaxf(x, -15.f), 15.f);
  float e = __expf(2.f * x);
  return (e - 1.f) / (e + 1.f);
}
__device__ __forceinline__ float lse2_(float a, float b) {
  float m = fmaxf(a, b);
  float d = fabsf(a - b);
  return m + log1pf(expf(-d));
}
// async global->LDS, 16B per lane; lds dest wave-uniform, src per-lane
__device__ __forceinline__ void gload16(const void* g, void* l) {
  __builtin_amdgcn_global_load_lds(
      (const __attribute__((address_space(1))) void*)g,
      (__attribute__((address_space(3))) void*)l, 16, 0, 0);
}

// Fragment-swizzled weight index (f16 units). Fragment line = 16 gate-rows x 8 k
// grouped 4 k-slots per 32-k MFMA tile: contiguous 1024B per (gr16, k32) block,
// within-block byte = lane*16 where lane = ((k>>3)&3)*16 + (gr&15).
__device__ __forceinline__ size_t wf_off(int q, int k, int K) {
  return ((size_t)(q >> 4) * (K >> 5) + (k >> 5)) * 512 +
         (size_t)(((k >> 3) & 3) * 128 + (q & 15) * 8 + (k & 7));
}

// ---------------------------------------------------------------------------
// BatchNorm statistics
// ---------------------------------------------------------------------------
__global__ __launch_bounds__(256) void bn_partial(const float* __restrict__ x,
                                                  float* __restrict__ psum,
                                                  float* __restrict__ psum2) {
  int d = blockIdx.x * 256 + threadIdx.x;          // 0..767
  int chunk = blockIdx.y;                          // 0..255
  const float* p = x + (size_t)chunk * 256 * 768 + d;
  float s = 0.f, s2 = 0.f;
  #pragma unroll 8
  for (int r = 0; r < 256; ++r) {
    float v = p[(size_t)r * 768];
    s += v;
    s2 = fmaf(v, v, s2);
  }
  psum[(size_t)chunk * 768 + d] = s;
  psum2[(size_t)chunk * 768 + d] = s2;
}

__global__ __launch_bounds__(256) void bn_finalize(const float* __restrict__ gamma,
                                                   const float* __restrict__ beta,
                                                   const float* __restrict__ psum,
                                                   const float* __restrict__ psum2,
                                                   float* __restrict__ sf_out,
                                                   float* __restrict__ tf_out) {
  int d = blockIdx.x * 256 + threadIdx.x;
  float s = 0.f, s2 = 0.f;
  for (int c = 0; c < 256; ++c) {
    s  += psum[(size_t)c * 768 + d];
    s2 += psum2[(size_t)c * 768 + d];
  }
  float mu  = s  * (1.f / NROWS);
  float var = s2 * (1.f / NROWS) - mu * mu;
  float sf  = rsqrtf(var + 1e-5f) * gamma[d];
  sf_out[d] = sf;
  tf_out[d] = beta[d] - mu * sf;
}

// ---------------------------------------------------------------------------
// Weight prep L0: gather i,g,o rows, fold BN scale, split fp16 h/l,
// store fragment-swizzled, fold BN shift into bias. q = sect*512+dir*256+jj
// ---------------------------------------------------------------------------
__global__ __launch_bounds__(256) void prep_w0(const float* __restrict__ w,
                                               const float* __restrict__ b_ih,
                                               const float* __restrict__ b_hh,
                                               const float* __restrict__ sf,
                                               const float* __restrict__ tf,
                                               _Float16* __restrict__ wh,
                                               _Float16* __restrict__ wl,
                                               float* __restrict__ bg) {
  int q = blockIdx.x;
  int s = q >> 9, j = q & 511, dir = j >> 8, jj = j & 255;
  int goff = (s == 0) ? 0 : ((s == 1) ? 512 : 768);
  int row = dir * 1024 + goff + jj;
  const float* src = w + (size_t)row * 768;
  float acc = 0.f;
  for (int d = threadIdx.x; d < 768; d += 256) {
    float wv = src[d];
    float wf = wv * sf[d];
    _Float16 h = (_Float16)wf;
    size_t o = wf_off(q, d, 768);
    wh[o] = h;
    wl[o] = (_Float16)(wf - (float)h);
    acc = fmaf(wv, tf[d], acc);
  }
  for (int off = 32; off; off >>= 1) acc += __shfl_down(acc, off);
  __shared__ float red[4];
  if ((threadIdx.x & 63) == 0) red[threadIdx.x >> 6] = acc;
  __syncthreads();
  if (threadIdx.x == 0)
    bg[q] = red[0] + red[1] + red[2] + red[3] + b_ih[row] + b_hh[row];
}

// Weight prep L1: gather + split + fragment-swizzle (no BN fold)
__global__ __launch_bounds__(256) void prep_w1(const float* __restrict__ w,
                                               const float* __restrict__ b_ih,
                                               const float* __restrict__ b_hh,
                                               _Float16* __restrict__ wh,
                                               _Float16* __restrict__ wl,
                                               float* __restrict__ bg) {
  int q = blockIdx.x;
  int s = q >> 9, j = q & 511, dir = j >> 8, jj = j & 255;
  int goff = (s == 0) ? 0 : ((s == 1) ? 512 : 768);
  int row = dir * 1024 + goff + jj;
  const float* src = w + (size_t)row * 512;
  for (int d = threadIdx.x; d < 512; d += 256) {
    float wv = src[d];
    _Float16 h = (_Float16)wv;
    size_t o = wf_off(q, d, 512);
    wh[o] = h;
    wl[o] = (_Float16)(wv - (float)h);
  }
  if (threadIdx.x == 0) bg[q] = b_ih[row] + b_hh[row];
}

// e[n][t] = fc_b[t]; zero num accumulator
__global__ __launch_bounds__(256) void init_misc(const float* __restrict__ fc_b,
                                                 float* __restrict__ e,
                                                 float* __restrict__ num) {
  int i = blockIdx.x * 256 + threadIdx.x;
  if (i < NROWS * 2) e[i] = fc_b[i & 1];
  if (i == 0) num[0] = 0.f;
}

// ---------------------------------------------------------------------------
// MFMA step over a BK=64 tile, fragment-linear LDS (conflict-free reads).
// Wave tile: 64 rows x 32 hcols x 3 gates; 144 MFMA per call.
// ---------------------------------------------------------------------------
__device__ __forceinline__ void mfma_step(const char* AhB, const char* AlB,
                                          const char* BhB, const char* BlB,
                                          int lane16, int wm, int wc,
                                          f32x4 acc[4][3][2]) {
  #pragma unroll
  for (int kk = 0; kk < 2; ++kk) {
    f16x8 ah[4], al[4];
    #pragma unroll
    for (int mf = 0; mf < 4; ++mf) {
      int ln = ((wm * 4 + mf) * 2 + kk) * 1024 + lane16;
      ah[mf] = *(const f16x8*)(AhB + ln);
      al[mf] = *(const f16x8*)(AlB + ln);
    }
    #pragma unroll
    for (int s = 0; s < 3; ++s)
      #pragma unroll
      for (int jf = 0; jf < 2; ++jf) {
        int ln = ((s * 4 + wc * 2 + jf) * 2 + kk) * 1024 + lane16;
        f16x8 bh = *(const f16x8*)(BhB + ln);
        f16x8 bl = *(const f16x8*)(BlB + ln);
        #pragma unroll
        for (int mf = 0; mf < 4; ++mf) {
          acc[mf][s][jf] = __builtin_amdgcn_mfma_f32_16x16x32_f16(ah[mf], bh, acc[mf][s][jf], 0, 0, 0);
          acc[mf][s][jf] = __builtin_amdgcn_mfma_f32_16x16x32_f16(ah[mf], bl, acc[mf][s][jf], 0, 0, 0);
          acc[mf][s][jf] = __builtin_amdgcn_mfma_f32_16x16x32_f16(al[mf], bh, acc[mf][s][jf], 0, 0, 0);
        }
      }
  }
}

// Stage A tile (128 rows x 64 k, f32 src) -> split fp16 h/l -> fragment-linear LDS
template <int K>
__device__ __forceinline__ void stage_A(const float* __restrict__ Arow0,
                                        int k0, int tid,
                                        char* AhB, char* AlB) {
  #pragma unroll
  for (int p = 0; p < 4; ++p) {
    int idx = p * 256 + tid;        // 0..1023
    int row = idx >> 3, ks = idx & 7;
    const float* src = Arow0 + (size_t)row * K + k0 + ks * 8;
    const float4 v0 = *(const float4*)src;
    const float4 v1 = *(const float4*)(src + 4);
    f16x8 hv, lv;
    hv[0] = (_Float16)v0.x; lv[0] = (_Float16)(v0.x - (float)hv[0]);
    hv[1] = (_Float16)v0.y; lv[1] = (_Float16)(v0.y - (float)hv[1]);
    hv[2] = (_Float16)v0.z; lv[2] = (_Float16)(v0.z - (float)hv[2]);
    hv[3] = (_Float16)v0.w; lv[3] = (_Float16)(v0.w - (float)hv[3]);
    hv[4] = (_Float16)v1.x; lv[4] = (_Float16)(v1.x - (float)hv[4]);
    hv[5] = (_Float16)v1.y; lv[5] = (_Float16)(v1.y - (float)hv[5]);
    hv[6] = (_Float16)v1.z; lv[6] = (_Float16)(v1.z - (float)hv[6]);
    hv[7] = (_Float16)v1.w; lv[7] = (_Float16)(v1.w - (float)hv[7]);
    int waddr = ((row >> 4) * 2 + (ks >> 2)) * 1024 + (ks & 3) * 256 + (row & 15) * 16;
    *(f16x8*)(AhB + waddr) = hv;
    *(f16x8*)(AlB + waddr) = lv;
  }
}

// Stage B tile (192 gate-rows x 64 k) from fragment-swizzled W: linear gload16
template <int K>
__device__ __forceinline__ void stage_B(const _Float16* __restrict__ Wh,
                                        const _Float16* __restrict__ Wl,
                                        int c0, int k0, int wvid, int lane,
                                        char* BhB, char* BlB) {
  const int lane8 = lane * 8;       // f16 units
  #pragma unroll
  for (int it = 0; it < 6; ++it) {
    int l24 = wvid + it * 4;        // 0..23: ((s*4+rb)*2 + kh)
    int kh = l24 & 1, srb = l24 >> 1;
    int s = srb >> 2, rb = srb & 3;
    int grb = s * 32 + (c0 >> 4) + rb;
    size_t src = ((size_t)grb * (K >> 5) + (k0 >> 5) + kh) * 512 + lane8;
    gload16(Wh + src, BhB + l24 * 1024);
    gload16(Wl + src, BlB + l24 * 1024);
  }
}

// ---------------------------------------------------------------------------
// GEMM1: gates = x @ W1' ; epilogue LSTM -> H (f32 row-major). Grid (8,512).
// ---------------------------------------------------------------------------
__global__ __launch_bounds__(256, 2) void gemm1(const float* __restrict__ A,
                                                const _Float16* __restrict__ Wh,
                                                const _Float16* __restrict__ Wl,
                                                const float* __restrict__ bg,
                                                float* __restrict__ H) {
  constexpr int K = 768;
  __shared__ __align__(16) char AhB[16384], AlB[16384];
  __shared__ __align__(16) char BhB[24576], BlB[24576];

  const int tid = threadIdx.x;
  const int lane = tid & 63, wvid = tid >> 6;
  const int l15 = lane & 15, lhi = lane >> 4;
  const int wm = wvid >> 1, wc = wvid & 1;
  const int lane16 = lane * 16;

  int bid = blockIdx.y * 8 + blockIdx.x;
  int wid = (bid & 7) * 512 + (bid >> 3);      // XCD-bijective swizzle
  const int m0 = (wid >> 3) * 128;
  const int c0 = (wid & 7) * 64;
  const float* Arow0 = A + (size_t)m0 * K;

  f32x4 acc[4][3][2] = {};

  for (int k0 = 0; k0 < K; k0 += 64) {
    stage_B<K>(Wh, Wl, c0, k0, wvid, lane, BhB, BlB);
    stage_A<K>(Arow0, k0, tid, AhB, AlB);
    __syncthreads();
    mfma_step(AhB, AlB, BhB, BlB, lane16, wm, wc, acc);
    __syncthreads();
  }

  // epilogue: LSTM cell (f-gate dead, c0=h0=0) -> h -> f32 H
  const int rb = m0 + wm * 64 + lhi * 4;
  #pragma unroll
  for (int mf = 0; mf < 4; ++mf)
    #pragma unroll
    for (int jf = 0; jf < 2; ++jf) {
      const int hcol = c0 + wc * 32 + jf * 16 + l15;
      const float bi = bg[hcol], bgv = bg[512 + hcol], bo = bg[1024 + hcol];
      #pragma unroll
      for (int r = 0; r < 4; ++r) {
        float gi = acc[mf][0][jf][r] + bi;
        float gg = acc[mf][1][jf][r] + bgv;
        float go = acc[mf][2][jf][r] + bo;
        float cv = sigm_(gi) * tanh_(gg);
        H[(size_t)(rb + mf * 16 + r) * 512 + hcol] = sigm_(go) * tanh_(cv);
      }
    }
}

// ---------------------------------------------------------------------------
// GEMM2: gates = h1 @ W2' ; A = H (f32) reg-staged like gemm1.
// Epilogue: LSTM -> fused FC -> atomicAdd into e. Grid (8,512).
// ---------------------------------------------------------------------------
__global__ __launch_bounds__(256, 2) void gemm2(const float* __restrict__ A,
                                                const _Float16* __restrict__ Wh,
                                                const _Float16* __restrict__ Wl,
                                                const float* __restrict__ bg,
                                                const float* __restrict__ fcw,
                                                float* __restrict__ ew) {
  constexpr int K = 512;
  __shared__ __align__(16) char AhB[16384], AlB[16384];
  __shared__ __align__(16) char BhB[24576], BlB[24576];

  const int tid = threadIdx.x;
  const int lane = tid & 63, wvid = tid >> 6;
  const int l15 = lane & 15, lhi = lane >> 4;
  const int wm = wvid >> 1, wc = wvid & 1;
  const int lane16 = lane * 16;

  int bid = blockIdx.y * 8 + blockIdx.x;
  int wid = (bid & 7) * 512 + (bid >> 3);
  const int m0 = (wid >> 3) * 128;
  const int c0 = (wid & 7) * 64;
  const float* Arow0 = A + (size_t)m0 * K;

  f32x4 acc[4][3][2] = {};

  for (int k0 = 0; k0 < K; k0 += 64) {
    stage_B<K>(Wh, Wl, c0, k0, wvid, lane, BhB, BlB);
    stage_A<K>(Arow0, k0, tid, AhB, AlB);
    __syncthreads();
    mfma_step(AhB, AlB, BhB, BlB, lane16, wm, wc, acc);
    __syncthreads();
  }

  // epilogue: LSTM act, fused FC (2 outputs), 16-lane reduce, atomicAdd
  const int rb = m0 + wm * 64 + lhi * 4;
  #pragma unroll
  for (int mf = 0; mf < 4; ++mf) {
    float pe0[4] = {0.f, 0.f, 0.f, 0.f}, pe1[4] = {0.f, 0.f, 0.f, 0.f};
    #pragma unroll
    for (int jf = 0; jf < 2; ++jf) {
      const int hcol = c0 + wc * 32 + jf * 16 + l15;
      const float bi = bg[hcol], bgv = bg[512 + hcol], bo = bg[1024 + hcol];
      const float f0 = fcw[hcol], f1 = fcw[512 + hcol];
      #pragma unroll
      for (int r = 0; r < 4; ++r) {
        float gi = acc[mf][0][jf][r] + bi;
        float gg = acc[mf][1][jf][r] + bgv;
        float go = acc[mf][2][jf][r] + bo;
        float cv = sigm_(gi) * tanh_(gg);
        float h  = sigm_(go) * tanh_(cv);
        pe0[r] = fmaf(h, f0, pe0[r]);
        pe1[r] = fmaf(h, f1, pe1[r]);
      }
    }
    #pragma unroll
    for (int r = 0; r < 4; ++r) {
      float a0 = pe0[r], a1 = pe1[r];
      #pragma unroll
      for (int off = 1; off < 16; off <<= 1) {
        a0 += __shfl_xor(a0, off);
        a1 += __shfl_xor(a1, off);
      }
      if (l15 == 0) {
        int rowg = rb + mf * 16 + r;
        atomicAdd(&ew[(size_t)rowg * 2 + 0], a0);
        atomicAdd(&ew[(size_t)rowg * 2 + 1], a1);
      }
    }
  }
}

// ---------------------------------------------------------------------------
// CRF: log-semiring 2x2 partial products (64 steps/thread) + num terms
// ---------------------------------------------------------------------------
__global__ __launch_bounds__(256) void crf_partial(const float* __restrict__ ew,
                                                   const int* __restrict__ labels,
                                                   const float* __restrict__ trans,
                                                   float* __restrict__ pmat,
                                                   float* __restrict__ numacc) {
  int g = blockIdx.x * 256 + threadIdx.x;   // 0..1023
  int t0 = 1 + g * 64;
  int t1 = t0 + 64; if (t1 > NROWS) t1 = NROWS;
  const float t00 = trans[0], t01 = trans[1], t10 = trans[2], t11 = trans[3];
  float p00 = 0.f, p01 = -1e30f, p10 = -1e30f, p11 = 0.f;   // identity
  float num = 0.f;
  int prev = labels[t0 - 1];
  for (int t = t0; t < t1; ++t) {
    float e0 = ew[(size_t)t * 2], e1 = ew[(size_t)t * 2 + 1];
    float m00 = t00 + e0, m01 = t01 + e1, m10 = t10 + e0, m11 = t11 + e1;
    float n00 = lse2_(p00 + m00, p01 + m10);
    float n01 = lse2_(p00 + m01, p01 + m11);
    float n10 = lse2_(p10 + m00, p11 + m10);
    float n11 = lse2_(p10 + m01, p11 + m11);
    p00 = n00; p01 = n01; p10 = n10; p11 = n11;
    int cur = labels[t];
    num += (cur ? e1 : e0) + trans[prev * 2 + cur];
    prev = cur;
  }
  float* pm = pmat + (size_t)g * 4;
  pm[0] = p00; pm[1] = p01; pm[2] = p10; pm[3] = p11;
  for (int off = 32; off; off >>= 1) num += __shfl_down(num, off);
  if ((threadIdx.x & 63) == 0) atomicAdd(numacc, num);
}

__global__ __launch_bounds__(256) void crf_final(const float* __restrict__ ew,
                                                 const int* __restrict__ labels,
                                                 const float* __restrict__ cstart,
                                                 const float* __restrict__ cend,
                                                 const float* __restrict__ pmat,
                                                 const float* __restrict__ numacc,
                                                 float* __restrict__ out) {
  __shared__ float sm[256][4];
  int t = threadIdx.x;
  const float* pm = pmat + (size_t)t * 16;
  float p00 = pm[0], p01 = pm[1], p10 = pm[2], p11 = pm[3];
  #pragma unroll
  for (int u = 1; u < 4; ++u) {
    const float* q = pm + u * 4;
    float b00 = q[0], b01 = q[1], b10 = q[2], b11 = q[3];
    float n00 = lse2_(p00 + b00, p01 + b10);
    float n01 = lse2_(p00 + b01, p01 + b11);
    float n10 = lse2_(p10 + b00, p11 + b10);
    float n11 = lse2_(p10 + b01, p11 + b11);
    p00 = n00; p01 = n01; p10 = n10; p11 = n11;
  }
  sm[t][0] = p00; sm[t][1] = p01; sm[t][2] = p10; sm[t][3] = p11;
  __syncthreads();
  for (int s = 1; s < 256; s <<= 1) {
    int i = t * (s << 1);
    if (i + s < 256) {
      float a00 = sm[i][0], a01 = sm[i][1], a10 = sm[i][2], a11 = sm[i][3];
      float b00 = sm[i + s][0], b01 = sm[i + s][1], b10 = sm[i + s][2], b11 = sm[i + s][3];
      sm[i][0] = lse2_(a00 + b00, a01 + b10);
      sm[i][1] = lse2_(a00 + b01, a01 + b11);
      sm[i][2] = lse2_(a10 + b00, a11 + b10);
      sm[i][3] = lse2_(a10 + b01, a11 + b11);
    }
    __syncthreads();
  }
  if (t == 0) {
    float a0 = cstart[0] + ew[0];
    float a1 = cstart[1] + ew[1];
    float aN0 = lse2_(a0 + sm[0][0], a1 + sm[0][2]);
    float aN1 = lse2_(a0 + sm[0][1], a1 + sm[0][3]);
    float den = lse2_(aN0 + cend[0], aN1 + cend[1]);
    int tag0 = labels[0], tagN = labels[NROWS - 1];
    float num = numacc[0] + cstart[tag0] + ew[tag0] + cend[tagN];
    out[0] = den - num;   // loss = -(num - den)
  }
}

__global__ __launch_bounds__(256) void copy_logits(const float* __restrict__ ew,
                                                   float* __restrict__ out) {
  int i = blockIdx.x * 256 + threadIdx.x;
  if (i < NROWS * 2) out[1 + i] = ew[i];
}

// ---------------------------------------------------------------------------
// Launch
// ---------------------------------------------------------------------------
extern "C" void kernel_launch(void* const* d_in, const int* in_sizes, int n_in,
                              void* d_out, int out_size, void* d_ws, size_t ws_size,
                              hipStream_t stream) {
  const float* x        = (const float*)d_in[0];
  const float* gamma    = (const float*)d_in[1];
  const float* beta     = (const float*)d_in[2];
  const float* w_ih_l0  = (const float*)d_in[3];
  // d_in[4] w_hh_l0: dead (h0 == 0)
  const float* b_ih_l0  = (const float*)d_in[5];
  const float* b_hh_l0  = (const float*)d_in[6];
  const float* w_ih_l1  = (const float*)d_in[7];
  // d_in[8] w_hh_l1: dead
  const float* b_ih_l1  = (const float*)d_in[9];
  const float* b_hh_l1  = (const float*)d_in[10];
  const float* fc_w     = (const float*)d_in[11];
  const float* fc_b     = (const float*)d_in[12];
  const float* crf_start= (const float*)d_in[13];
  const float* crf_end  = (const float*)d_in[14];
  const float* crf_trans= (const float*)d_in[15];
  const int*   labels   = (const int*)d_in[16];

  char* ws   = (char*)d_ws;
  float* out = (float*)d_out;

  float*     bg0  = (float*)(ws + OB_BG0);
  float*     bg1  = (float*)(ws + OB_BG1);
  _Float16*  w1h  = (_Float16*)(ws + OB_W1H);
  _Float16*  w1l  = (_Float16*)(ws + OB_W1L);
  _Float16*  w2h  = (_Float16*)(ws + OB_W2H);
  _Float16*  w2l  = (_Float16*)(ws + OB_W2L);
  float*     e    = (float*)(ws + OB_E);
  float*     pmat = (float*)(ws + OB_PMAT);
  float*     num  = (float*)(ws + OB_NUM);
  float*     H    = (float*)(ws + OB_H);
  float*     psum = (float*)(ws + OB_PSUM);
  float*     psum2= (float*)(ws + OB_PSUM2);
  float*     sf   = (float*)(ws + OB_SF);
  float*     tf   = (float*)(ws + OB_TF);

  bn_partial<<<dim3(3, 256), 256, 0, stream>>>(x, psum, psum2);
  bn_finalize<<<3, 256, 0, stream>>>(gamma, beta, psum, psum2, sf, tf);
  prep_w0<<<1536, 256, 0, stream>>>(w_ih_l0, b_ih_l0, b_hh_l0, sf, tf, w1h, w1l, bg0);
  prep_w1<<<1536, 256, 0, stream>>>(w_ih_l1, b_ih_l1, b_hh_l1, w2h, w2l, bg1);
  init_misc<<<512, 256, 0, stream>>>(fc_b, e, num);

  gemm1<<<dim3(8, 512), 256, 0, stream>>>(x, w1h, w1l, bg0, H);
  gemm2<<<dim3(8, 512), 256, 0, stream>>>(H, w2h, w2l, bg1, fc_w, e);

  crf_partial<<<4, 256, 0, stream>>>(e, labels, crf_trans, pmat, num);
  crf_final<<<1, 256, 0, stream>>>(e, labels, crf_start, crf_end, pmat, num, out);
  copy_logits<<<512, 256, 0, stream>>>(e, out);
}

// Round 4
// 1207.417 us; speedup vs baseline: 1.1150x; 1.1150x over previous
//
#include <hip/hip_runtime.h>

typedef _Float16 f16x8 __attribute__((ext_vector_type(8)));
typedef float f32x4 __attribute__((ext_vector_type(4)));

static constexpr int NROWS = 65536;

// ---------------------------------------------------------------------------
// Workspace byte offsets (total 142,635,264 B)
// ---------------------------------------------------------------------------
static constexpr size_t OB_BG0  = 0;                        // 1536*4
static constexpr size_t OB_BG1  = OB_BG0 + 6144;            // 1536*4
static constexpr size_t OB_W1H  = OB_BG1 + 6144;            // 1536*768*2 (frag-swizzled)
static constexpr size_t OB_W1L  = OB_W1H + 2359296;
static constexpr size_t OB_W2H  = OB_W1L + 2359296;         // 1536*512*2 (frag-swizzled)
static constexpr size_t OB_W2L  = OB_W2H + 1572864;
static constexpr size_t OB_E    = OB_W2L + 1572864;         // 65536*2*4
static constexpr size_t OB_PMAT = OB_E + 524288;            // 1024*4*4
static constexpr size_t OB_NUM  = OB_PMAT + 16384;          // 256 (padded)
static constexpr size_t OB_HH   = OB_NUM + 256;             // 65536*512*2 (frag-swizzled fp16)
static constexpr size_t OB_HL   = OB_HH + 67108864;         // 65536*512*2
// Aliased into the H region — all consumers finish before gemm1 writes H:
static constexpr size_t OB_PSUM  = OB_HH;                   // 256*768*4
static constexpr size_t OB_PSUM2 = OB_PSUM + 786432;        // 256*768*4
static constexpr size_t OB_SF    = OB_PSUM2 + 786432;       // 768*4
static constexpr size_t OB_TF    = OB_SF + 3072;            // 768*4

// ---------------------------------------------------------------------------
// Helpers
// ---------------------------------------------------------------------------
__device__ __forceinline__ float sigm_(float x) { return 1.f / (1.f + __expf(-x)); }
__device__ __forceinline__ float tanh_(float x) {
  x = fminf(fmaxf(x, -15.f), 15.f);
  float e = __expf(2.f * x);
  return (e - 1.f) / (e + 1.f);
}
__device__ __forceinline__ float lse2_(float a, float b) {
  float m = fmaxf(a, b);
  float d = fabsf(a - b);
  return m + log1pf(expf(-d));
}
// async global->LDS, 16B per lane; lds dest wave-uniform (lane*16 implicit)
__device__ __forceinline__ void gload16(const void* g, void* l) {
  __builtin_amdgcn_global_load_lds(
      (const __attribute__((address_space(1))) void*)g,
      (__attribute__((address_space(3))) void*)l, 16, 0, 0);
}

// Fragment-swizzled index (f16 units) for a row-major [R][K] matrix:
// 1024-B block per (16 rows x 32 k); within-block f16 = kslot*128 + row15*8 + k7.
__device__ __forceinline__ size_t frag_off(int row, int k, int K) {
  return ((size_t)(row >> 4) * (K >> 5) + (k >> 5)) * 512 +
         (size_t)(((k >> 3) & 3) * 128 + (row & 15) * 8 + (k & 7));
}

// ---------------------------------------------------------------------------
// BatchNorm statistics
// ---------------------------------------------------------------------------
__global__ __launch_bounds__(256) void bn_partial(const float* __restrict__ x,
                                                  float* __restrict__ psum,
                                                  float* __restrict__ psum2) {
  int d = blockIdx.x * 256 + threadIdx.x;          // 0..767
  int chunk = blockIdx.y;                          // 0..255
  const float* p = x + (size_t)chunk * 256 * 768 + d;
  float s = 0.f, s2 = 0.f;
  #pragma unroll 8
  for (int r = 0; r < 256; ++r) {
    float v = p[(size_t)r * 768];
    s += v;
    s2 = fmaf(v, v, s2);
  }
  psum[(size_t)chunk * 768 + d] = s;
  psum2[(size_t)chunk * 768 + d] = s2;
}

__global__ __launch_bounds__(256) void bn_finalize(const float* __restrict__ gamma,
                                                   const float* __restrict__ beta,
                                                   const float* __restrict__ psum,
                                                   const float* __restrict__ psum2,
                                                   float* __restrict__ sf_out,
                                                   float* __restrict__ tf_out) {
  int d = blockIdx.x * 256 + threadIdx.x;
  float s = 0.f, s2 = 0.f;
  for (int c = 0; c < 256; ++c) {
    s  += psum[(size_t)c * 768 + d];
    s2 += psum2[(size_t)c * 768 + d];
  }
  float mu  = s  * (1.f / NROWS);
  float var = s2 * (1.f / NROWS) - mu * mu;
  float sf  = rsqrtf(var + 1e-5f) * gamma[d];
  sf_out[d] = sf;
  tf_out[d] = beta[d] - mu * sf;
}

// ---------------------------------------------------------------------------
// Weight prep L0: gather i,g,o rows, fold BN scale, split fp16 h/l,
// store fragment-swizzled, fold BN shift into bias. q = sect*512+dir*256+jj
// ---------------------------------------------------------------------------
__global__ __launch_bounds__(256) void prep_w0(const float* __restrict__ w,
                                               const float* __restrict__ b_ih,
                                               const float* __restrict__ b_hh,
                                               const float* __restrict__ sf,
                                               const float* __restrict__ tf,
                                               _Float16* __restrict__ wh,
                                               _Float16* __restrict__ wl,
                                               float* __restrict__ bg) {
  int q = blockIdx.x;
  int s = q >> 9, j = q & 511, dir = j >> 8, jj = j & 255;
  int goff = (s == 0) ? 0 : ((s == 1) ? 512 : 768);
  int row = dir * 1024 + goff + jj;
  const float* src = w + (size_t)row * 768;
  float acc = 0.f;
  for (int d = threadIdx.x; d < 768; d += 256) {
    float wv = src[d];
    float wf = wv * sf[d];
    _Float16 h = (_Float16)wf;
    size_t o = frag_off(q, d, 768);
    wh[o] = h;
    wl[o] = (_Float16)(wf - (float)h);
    acc = fmaf(wv, tf[d], acc);
  }
  for (int off = 32; off; off >>= 1) acc += __shfl_down(acc, off);
  __shared__ float red[4];
  if ((threadIdx.x & 63) == 0) red[threadIdx.x >> 6] = acc;
  __syncthreads();
  if (threadIdx.x == 0)
    bg[q] = red[0] + red[1] + red[2] + red[3] + b_ih[row] + b_hh[row];
}

// Weight prep L1: gather + split + fragment-swizzle (no BN fold)
__global__ __launch_bounds__(256) void prep_w1(const float* __restrict__ w,
                                               const float* __restrict__ b_ih,
                                               const float* __restrict__ b_hh,
                                               _Float16* __restrict__ wh,
                                               _Float16* __restrict__ wl,
                                               float* __restrict__ bg) {
  int q = blockIdx.x;
  int s = q >> 9, j = q & 511, dir = j >> 8, jj = j & 255;
  int goff = (s == 0) ? 0 : ((s == 1) ? 512 : 768);
  int row = dir * 1024 + goff + jj;
  const float* src = w + (size_t)row * 512;
  for (int d = threadIdx.x; d < 512; d += 256) {
    float wv = src[d];
    _Float16 h = (_Float16)wv;
    size_t o = frag_off(q, d, 512);
    wh[o] = h;
    wl[o] = (_Float16)(wv - (float)h);
  }
  if (threadIdx.x == 0) bg[q] = b_ih[row] + b_hh[row];
}

// e[n][t] = fc_b[t]; zero num accumulator
__global__ __launch_bounds__(256) void init_misc(const float* __restrict__ fc_b,
                                                 float* __restrict__ e,
                                                 float* __restrict__ num) {
  int i = blockIdx.x * 256 + threadIdx.x;
  if (i < NROWS * 2) e[i] = fc_b[i & 1];
  if (i == 0) num[0] = 0.f;
}

// ---------------------------------------------------------------------------
// MFMA step over a BK=64 tile, fragment-linear LDS (conflict-free reads).
// Wave tile: 64 rows x 32 hcols x 3 gates; 144 MFMA per call.
// ---------------------------------------------------------------------------
__device__ __forceinline__ void mfma_step(const char* AhB, const char* AlB,
                                          const char* BhB, const char* BlB,
                                          int lane16, int wm, int wc,
                                          f32x4 acc[4][3][2]) {
  #pragma unroll
  for (int kk = 0; kk < 2; ++kk) {
    f16x8 ah[4], al[4];
    #pragma unroll
    for (int mf = 0; mf < 4; ++mf) {
      int ln = ((wm * 4 + mf) * 2 + kk) * 1024 + lane16;
      ah[mf] = *(const f16x8*)(AhB + ln);
      al[mf] = *(const f16x8*)(AlB + ln);
    }
    #pragma unroll
    for (int s = 0; s < 3; ++s)
      #pragma unroll
      for (int jf = 0; jf < 2; ++jf) {
        int ln = ((s * 4 + wc * 2 + jf) * 2 + kk) * 1024 + lane16;
        f16x8 bh = *(const f16x8*)(BhB + ln);
        f16x8 bl = *(const f16x8*)(BlB + ln);
        #pragma unroll
        for (int mf = 0; mf < 4; ++mf) {
          acc[mf][s][jf] = __builtin_amdgcn_mfma_f32_16x16x32_f16(ah[mf], bh, acc[mf][s][jf], 0, 0, 0);
          acc[mf][s][jf] = __builtin_amdgcn_mfma_f32_16x16x32_f16(ah[mf], bl, acc[mf][s][jf], 0, 0, 0);
          acc[mf][s][jf] = __builtin_amdgcn_mfma_f32_16x16x32_f16(al[mf], bh, acc[mf][s][jf], 0, 0, 0);
        }
      }
  }
}

// Stage A (128x64 f32) -> split fp16 h/l -> fragment-linear LDS.
// Lane map: row15 fastest => each 16-lane group writes one contiguous 256-B
// k-slot row => zero write bank conflicts.
template <int K>
__device__ __forceinline__ void stage_A_split(const float* __restrict__ Arow0,
                                              int k0, int tid,
                                              char* AhB, char* AlB) {
  #pragma unroll
  for (int p = 0; p < 4; ++p) {
    int idx = p * 256 + tid;        // 0..1023
    int row15 = idx & 15;
    int ks    = (idx >> 4) & 7;     // k-octet within BK=64
    int rowg  = idx >> 7;           // 0..7
    const float* src = Arow0 + (size_t)(rowg * 16 + row15) * K + k0 + ks * 8;
    const float4 v0 = *(const float4*)src;
    const float4 v1 = *(const float4*)(src + 4);
    f16x8 hv, lv;
    hv[0] = (_Float16)v0.x; lv[0] = (_Float16)(v0.x - (float)hv[0]);
    hv[1] = (_Float16)v0.y; lv[1] = (_Float16)(v0.y - (float)hv[1]);
    hv[2] = (_Float16)v0.z; lv[2] = (_Float16)(v0.z - (float)hv[2]);
    hv[3] = (_Float16)v0.w; lv[3] = (_Float16)(v0.w - (float)hv[3]);
    hv[4] = (_Float16)v1.x; lv[4] = (_Float16)(v1.x - (float)hv[4]);
    hv[5] = (_Float16)v1.y; lv[5] = (_Float16)(v1.y - (float)hv[5]);
    hv[6] = (_Float16)v1.z; lv[6] = (_Float16)(v1.z - (float)hv[6]);
    hv[7] = (_Float16)v1.w; lv[7] = (_Float16)(v1.w - (float)hv[7]);
    int waddr = (rowg * 2 + (ks >> 2)) * 1024 + (ks & 3) * 256 + row15 * 16;
    *(f16x8*)(AhB + waddr) = hv;
    *(f16x8*)(AlB + waddr) = lv;
  }
}

// Stage A (128x64) from fragment-swizzled fp16 h/l global: pure linear DMA.
__device__ __forceinline__ void stage_A_gl(const _Float16* __restrict__ Hh,
                                           const _Float16* __restrict__ Hl,
                                           int m0, int k0, int wvid, int lane,
                                           char* AhB, char* AlB) {
  const int lane8 = lane * 8;       // f16 units
  #pragma unroll
  for (int it = 0; it < 4; ++it) {
    int blk = wvid + it * 4;        // 0..15 : rowg*2 + kk
    int rowg = blk >> 1, kk = blk & 1;
    size_t src = (((size_t)(m0 >> 4) + rowg) * 16 + (k0 >> 5) + kk) * 512 + lane8;
    gload16(Hh + src, AhB + blk * 1024);
    gload16(Hl + src, AlB + blk * 1024);
  }
}

// Stage B (192 gate-rows x 64 k) from fragment-swizzled W: pure linear DMA.
template <int K>
__device__ __forceinline__ void stage_B(const _Float16* __restrict__ Wh,
                                        const _Float16* __restrict__ Wl,
                                        int c0, int k0, int wvid, int lane,
                                        char* BhB, char* BlB) {
  const int lane8 = lane * 8;       // f16 units
  #pragma unroll
  for (int it = 0; it < 6; ++it) {
    int l24 = wvid + it * 4;        // 0..23: ((s*4+rb)*2 + kh)
    int kh = l24 & 1, srb = l24 >> 1;
    int s = srb >> 2, rb = srb & 3;
    int grb = s * 32 + (c0 >> 4) + rb;
    size_t src = ((size_t)grb * (K >> 5) + (k0 >> 5) + kh) * 512 + lane8;
    gload16(Wh + src, BhB + l24 * 1024);
    gload16(Wl + src, BlB + l24 * 1024);
  }
}

// ---------------------------------------------------------------------------
// GEMM1: gates = x @ W1' ; epilogue LSTM -> H (fp16 h/l, fragment-swizzled).
// Grid (8,512).
// ---------------------------------------------------------------------------
__global__ __launch_bounds__(256, 2) void gemm1(const float* __restrict__ A,
                                                const _Float16* __restrict__ Wh,
                                                const _Float16* __restrict__ Wl,
                                                const float* __restrict__ bg,
                                                _Float16* __restrict__ Hh,
                                                _Float16* __restrict__ Hl) {
  constexpr int K = 768;
  __shared__ __align__(16) char AhB[16384], AlB[16384];
  __shared__ __align__(16) char BhB[24576], BlB[24576];

  const int tid = threadIdx.x;
  const int lane = tid & 63, wvid = tid >> 6;
  const int l15 = lane & 15, lhi = lane >> 4;
  const int wm = wvid >> 1, wc = wvid & 1;
  const int lane16 = lane * 16;

  int bid = blockIdx.y * 8 + blockIdx.x;
  int wid = (bid & 7) * 512 + (bid >> 3);      // XCD-bijective swizzle
  const int m0 = (wid >> 3) * 128;
  const int c0 = (wid & 7) * 64;
  const float* Arow0 = A + (size_t)m0 * K;

  f32x4 acc[4][3][2] = {};

  for (int k0 = 0; k0 < K; k0 += 64) {
    stage_B<K>(Wh, Wl, c0, k0, wvid, lane, BhB, BlB);   // async DMA in flight
    stage_A_split<K>(Arow0, k0, tid, AhB, AlB);         // VALU work hides DMA
    __syncthreads();
    mfma_step(AhB, AlB, BhB, BlB, lane16, wm, wc, acc);
    __syncthreads();
  }

  // epilogue: LSTM cell (f-gate dead, c0=h0=0) -> h -> fp16 h/l frag-swizzled
  const int rb = m0 + wm * 64 + lhi * 4;
  #pragma unroll
  for (int mf = 0; mf < 4; ++mf)
    #pragma unroll
    for (int jf = 0; jf < 2; ++jf) {
      const int hcol = c0 + wc * 32 + jf * 16 + l15;
      const float bi = bg[hcol], bgv = bg[512 + hcol], bo = bg[1024 + hcol];
      const int cpart = ((hcol >> 3) & 3) * 128 + (hcol & 7);
      const size_t cblk = (size_t)(hcol >> 5);
      #pragma unroll
      for (int r = 0; r < 4; ++r) {
        int m = rb + mf * 16 + r;
        float gi = acc[mf][0][jf][r] + bi;
        float gg = acc[mf][1][jf][r] + bgv;
        float go = acc[mf][2][jf][r] + bo;
        float cv = sigm_(gi) * tanh_(gg);
        float h  = sigm_(go) * tanh_(cv);
        size_t o = ((size_t)(m >> 4) * 16 + cblk) * 512 + cpart + (m & 15) * 8;
        _Float16 h16 = (_Float16)h;
        Hh[o] = h16;
        Hl[o] = (_Float16)(h - (float)h16);
      }
    }
}

// ---------------------------------------------------------------------------
// GEMM2: gates = h1 @ W2' ; A from frag-swizzled fp16 H via pure DMA.
// Epilogue: LSTM -> fused FC -> atomicAdd into e. Grid (8,512).
// ---------------------------------------------------------------------------
__global__ __launch_bounds__(256, 2) void gemm2(const _Float16* __restrict__ Hh,
                                                const _Float16* __restrict__ Hl,
                                                const _Float16* __restrict__ Wh,
                                                const _Float16* __restrict__ Wl,
                                                const float* __restrict__ bg,
                                                const float* __restrict__ fcw,
                                                float* __restrict__ ew) {
  constexpr int K = 512;
  __shared__ __align__(16) char AhB[16384], AlB[16384];
  __shared__ __align__(16) char BhB[24576], BlB[24576];

  const int tid = threadIdx.x;
  const int lane = tid & 63, wvid = tid >> 6;
  const int l15 = lane & 15, lhi = lane >> 4;
  const int wm = wvid >> 1, wc = wvid & 1;
  const int lane16 = lane * 16;

  int bid = blockIdx.y * 8 + blockIdx.x;
  int wid = (bid & 7) * 512 + (bid >> 3);
  const int m0 = (wid >> 3) * 128;
  const int c0 = (wid & 7) * 64;

  f32x4 acc[4][3][2] = {};

  for (int k0 = 0; k0 < K; k0 += 64) {
    stage_A_gl(Hh, Hl, m0, k0, wvid, lane, AhB, AlB);
    stage_B<K>(Wh, Wl, c0, k0, wvid, lane, BhB, BlB);
    __syncthreads();
    mfma_step(AhB, AlB, BhB, BlB, lane16, wm, wc, acc);
    __syncthreads();
  }

  // epilogue: LSTM act, fused FC (2 outputs), 16-lane reduce, atomicAdd
  const int rb = m0 + wm * 64 + lhi * 4;
  #pragma unroll
  for (int mf = 0; mf < 4; ++mf) {
    float pe0[4] = {0.f, 0.f, 0.f, 0.f}, pe1[4] = {0.f, 0.f, 0.f, 0.f};
    #pragma unroll
    for (int jf = 0; jf < 2; ++jf) {
      const int hcol = c0 + wc * 32 + jf * 16 + l15;
      const float bi = bg[hcol], bgv = bg[512 + hcol], bo = bg[1024 + hcol];
      const float f0 = fcw[hcol], f1 = fcw[512 + hcol];
      #pragma unroll
      for (int r = 0; r < 4; ++r) {
        float gi = acc[mf][0][jf][r] + bi;
        float gg = acc[mf][1][jf][r] + bgv;
        float go = acc[mf][2][jf][r] + bo;
        float cv = sigm_(gi) * tanh_(gg);
        float h  = sigm_(go) * tanh_(cv);
        pe0[r] = fmaf(h, f0, pe0[r]);
        pe1[r] = fmaf(h, f1, pe1[r]);
      }
    }
    #pragma unroll
    for (int r = 0; r < 4; ++r) {
      float a0 = pe0[r], a1 = pe1[r];
      #pragma unroll
      for (int off = 1; off < 16; off <<= 1) {
        a0 += __shfl_xor(a0, off);
        a1 += __shfl_xor(a1, off);
      }
      if (l15 == 0) {
        int rowg = rb + mf * 16 + r;
        atomicAdd(&ew[(size_t)rowg * 2 + 0], a0);
        atomicAdd(&ew[(size_t)rowg * 2 + 1], a1);
      }
    }
  }
}

// ---------------------------------------------------------------------------
// CRF: log-semiring 2x2 partial products (64 steps/thread) + num terms
// ---------------------------------------------------------------------------
__global__ __launch_bounds__(256) void crf_partial(const float* __restrict__ ew,
                                                   const int* __restrict__ labels,
                                                   const float* __restrict__ trans,
                                                   float* __restrict__ pmat,
                                                   float* __restrict__ numacc) {
  int g = blockIdx.x * 256 + threadIdx.x;   // 0..1023
  int t0 = 1 + g * 64;
  int t1 = t0 + 64; if (t1 > NROWS) t1 = NROWS;
  const float t00 = trans[0], t01 = trans[1], t10 = trans[2], t11 = trans[3];
  float p00 = 0.f, p01 = -1e30f, p10 = -1e30f, p11 = 0.f;   // identity
  float num = 0.f;
  int prev = labels[t0 - 1];
  for (int t = t0; t < t1; ++t) {
    float e0 = ew[(size_t)t * 2], e1 = ew[(size_t)t * 2 + 1];
    float m00 = t00 + e0, m01 = t01 + e1, m10 = t10 + e0, m11 = t11 + e1;
    float n00 = lse2_(p00 + m00, p01 + m10);
    float n01 = lse2_(p00 + m01, p01 + m11);
    float n10 = lse2_(p10 + m00, p11 + m10);
    float n11 = lse2_(p10 + m01, p11 + m11);
    p00 = n00; p01 = n01; p10 = n10; p11 = n11;
    int cur = labels[t];
    num += (cur ? e1 : e0) + trans[prev * 2 + cur];
    prev = cur;
  }
  float* pm = pmat + (size_t)g * 4;
  pm[0] = p00; pm[1] = p01; pm[2] = p10; pm[3] = p11;
  for (int off = 32; off; off >>= 1) num += __shfl_down(num, off);
  if ((threadIdx.x & 63) == 0) atomicAdd(numacc, num);
}

__global__ __launch_bounds__(256) void crf_final(const float* __restrict__ ew,
                                                 const int* __restrict__ labels,
                                                 const float* __restrict__ cstart,
                                                 const float* __restrict__ cend,
                                                 const float* __restrict__ pmat,
                                                 const float* __restrict__ numacc,
                                                 float* __restrict__ out) {
  __shared__ float sm[256][4];
  int t = threadIdx.x;
  const float* pm = pmat + (size_t)t * 16;
  float p00 = pm[0], p01 = pm[1], p10 = pm[2], p11 = pm[3];
  #pragma unroll
  for (int u = 1; u < 4; ++u) {
    const float* q = pm + u * 4;
    float b00 = q[0], b01 = q[1], b10 = q[2], b11 = q[3];
    float n00 = lse2_(p00 + b00, p01 + b10);
    float n01 = lse2_(p00 + b01, p01 + b11);
    float n10 = lse2_(p10 + b00, p11 + b10);
    float n11 = lse2_(p10 + b01, p11 + b11);
    p00 = n00; p01 = n01; p10 = n10; p11 = n11;
  }
  sm[t][0] = p00; sm[t][1] = p01; sm[t][2] = p10; sm[t][3] = p11;
  __syncthreads();
  for (int s = 1; s < 256; s <<= 1) {
    int i = t * (s << 1);
    if (i + s < 256) {
      float a00 = sm[i][0], a01 = sm[i][1], a10 = sm[i][2], a11 = sm[i][3];
      float b00 = sm[i + s][0], b01 = sm[i + s][1], b10 = sm[i + s][2], b11 = sm[i + s][3];
      sm[i][0] = lse2_(a00 + b00, a01 + b10);
      sm[i][1] = lse2_(a00 + b01, a01 + b11);
      sm[i][2] = lse2_(a10 + b00, a11 + b10);
      sm[i][3] = lse2_(a10 + b01, a11 + b11);
    }
    __syncthreads();
  }
  if (t == 0) {
    float a0 = cstart[0] + ew[0];
    float a1 = cstart[1] + ew[1];
    float aN0 = lse2_(a0 + sm[0][0], a1 + sm[0][2]);
    float aN1 = lse2_(a0 + sm[0][1], a1 + sm[0][3]);
    float den = lse2_(aN0 + cend[0], aN1 + cend[1]);
    int tag0 = labels[0], tagN = labels[NROWS - 1];
    float num = numacc[0] + cstart[tag0] + ew[tag0] + cend[tagN];
    out[0] = den - num;   // loss = -(num - den)
  }
}

__global__ __launch_bounds__(256) void copy_logits(const float* __restrict__ ew,
                                                   float* __restrict__ out) {
  int i = blockIdx.x * 256 + threadIdx.x;
  if (i < NROWS * 2) out[1 + i] = ew[i];
}

// ---------------------------------------------------------------------------
// Launch
// ---------------------------------------------------------------------------
extern "C" void kernel_launch(void* const* d_in, const int* in_sizes, int n_in,
                              void* d_out, int out_size, void* d_ws, size_t ws_size,
                              hipStream_t stream) {
  const float* x        = (const float*)d_in[0];
  const float* gamma    = (const float*)d_in[1];
  const float* beta     = (const float*)d_in[2];
  const float* w_ih_l0  = (const float*)d_in[3];
  // d_in[4] w_hh_l0: dead (h0 == 0)
  const float* b_ih_l0  = (const float*)d_in[5];
  const float* b_hh_l0  = (const float*)d_in[6];
  const float* w_ih_l1  = (const float*)d_in[7];
  // d_in[8] w_hh_l1: dead
  const float* b_ih_l1  = (const float*)d_in[9];
  const float* b_hh_l1  = (const float*)d_in[10];
  const float* fc_w     = (const float*)d_in[11];
  const float* fc_b     = (const float*)d_in[12];
  const float* crf_start= (const float*)d_in[13];
  const float* crf_end  = (const float*)d_in[14];
  const float* crf_trans= (const float*)d_in[15];
  const int*   labels   = (const int*)d_in[16];

  char* ws   = (char*)d_ws;
  float* out = (float*)d_out;

  float*     bg0  = (float*)(ws + OB_BG0);
  float*     bg1  = (float*)(ws + OB_BG1);
  _Float16*  w1h  = (_Float16*)(ws + OB_W1H);
  _Float16*  w1l  = (_Float16*)(ws + OB_W1L);
  _Float16*  w2h  = (_Float16*)(ws + OB_W2H);
  _Float16*  w2l  = (_Float16*)(ws + OB_W2L);
  float*     e    = (float*)(ws + OB_E);
  float*     pmat = (float*)(ws + OB_PMAT);
  float*     num  = (float*)(ws + OB_NUM);
  _Float16*  hh   = (_Float16*)(ws + OB_HH);
  _Float16*  hl   = (_Float16*)(ws + OB_HL);
  float*     psum = (float*)(ws + OB_PSUM);
  float*     psum2= (float*)(ws + OB_PSUM2);
  float*     sf   = (float*)(ws + OB_SF);
  float*     tf   = (float*)(ws + OB_TF);

  bn_partial<<<dim3(3, 256), 256, 0, stream>>>(x, psum, psum2);
  bn_finalize<<<3, 256, 0, stream>>>(gamma, beta, psum, psum2, sf, tf);
  prep_w0<<<1536, 256, 0, stream>>>(w_ih_l0, b_ih_l0, b_hh_l0, sf, tf, w1h, w1l, bg0);
  prep_w1<<<1536, 256, 0, stream>>>(w_ih_l1, b_ih_l1, b_hh_l1, w2h, w2l, bg1);
  init_misc<<<512, 256, 0, stream>>>(fc_b, e, num);

  gemm1<<<dim3(8, 512), 256, 0, stream>>>(x, w1h, w1l, bg0, hh, hl);
  gemm2<<<dim3(8, 512), 256, 0, stream>>>(hh, hl, w2h, w2l, bg1, fc_w, e);

  crf_partial<<<4, 256, 0, stream>>>(e, labels, crf_trans, pmat, num);
  crf_final<<<1, 256, 0, stream>>>(e, labels, crf_start, crf_end, pmat, num, out);
  copy_logits<<<512, 256, 0, stream>>>(e, out);
}